// Round 12
// baseline (200.832 us; speedup 1.0000x reference)
//
#include <hip/hip_runtime.h>
#include <cstddef>
#include <cstdint>

#define TS 2048   // sequence length S
#define TD 512    // model dim D
#define TH 8      // heads
#define TDH 64    // head dim
#define CAP 256   // support entries per head list (ballot fallback beyond)

typedef float f32x4 __attribute__((ext_vector_type(4)));
typedef short short8v __attribute__((ext_vector_type(8)));
typedef _Float16 half4v __attribute__((ext_vector_type(4)));
typedef _Float16 half8v __attribute__((ext_vector_type(8)));

__device__ __forceinline__ unsigned short f2bf(float f) {
  unsigned u = __builtin_bit_cast(unsigned, f);
  u += 0x7fff + ((u >> 16) & 1);          // RNE
  return (unsigned short)(u >> 16);
}

// ---------------------------------------------------------------------------
// gemm128: C[4096,512] = A[4096,512] @ W[512,512] + bias. BM=64, BN=128,
// BK=32, 4 waves side-by-side (wave = 64x32 output = 4x2 MFMA tiles).
// A: f32 (aIsBf16=0) or bf16. mode 0: f32 row-major; mode 1: bf16 head-major.
// Frag convention (proven R6-R11): both operands loaded as [16 rows=lc16][k=g*8];
// D row (first op) = g*4+r, D col (second op) = lc16.
// ---------------------------------------------------------------------------
__global__ __launch_bounds__(256) void gemm128(
    const void* __restrict__ A, int aIsBf16,
    const float* __restrict__ W, const float* __restrict__ bias,
    float* __restrict__ Cf, short* __restrict__ Cbf, int mode)
{
  __shared__ short As[64][40];
  __shared__ short Bs[128][40];

  const int tid  = threadIdx.x;
  const int w    = tid >> 6;
  const int lane = tid & 63;
  const int g    = lane >> 4;
  const int lc16 = lane & 15;
  const int row0 = blockIdx.x * 64;
  const int col0 = blockIdx.y * 128;

  const int ar = tid >> 2;            // A row 0..63
  const int ak = (tid & 3) << 3;      // A k 0,8,16,24
  const int bk = tid >> 3;            // W k-row 0..31
  const int bn = (tid & 7) << 4;      // W n 0..112 (16 cols each)

  f32x4 acc[4][2];
#pragma unroll
  for (int i = 0; i < 4; ++i)
#pragma unroll
    for (int j = 0; j < 2; ++j) acc[i][j] = (f32x4){0.f, 0.f, 0.f, 0.f};

  for (int kt = 0; kt < TD; kt += 32) {
    if (aIsBf16) {
      short8v v = *(const short8v*)((const short*)A + (size_t)(row0 + ar) * TD + kt + ak);
      *(short8v*)&As[ar][ak] = v;
    } else {
      const float* ap = (const float*)A + (size_t)(row0 + ar) * TD + kt + ak;
      float4 f0 = *(const float4*)ap;
      float4 f1 = *(const float4*)(ap + 4);
      short8v v;
      v[0] = (short)f2bf(f0.x); v[1] = (short)f2bf(f0.y);
      v[2] = (short)f2bf(f0.z); v[3] = (short)f2bf(f0.w);
      v[4] = (short)f2bf(f1.x); v[5] = (short)f2bf(f1.y);
      v[6] = (short)f2bf(f1.z); v[7] = (short)f2bf(f1.w);
      *(short8v*)&As[ar][ak] = v;
    }
    {
      const float* wp = W + (size_t)(kt + bk) * TD + col0 + bn;
      float4 f0 = *(const float4*)wp;
      float4 f1 = *(const float4*)(wp + 4);
      float4 f2 = *(const float4*)(wp + 8);
      float4 f3 = *(const float4*)(wp + 12);
      Bs[bn +  0][bk] = (short)f2bf(f0.x);
      Bs[bn +  1][bk] = (short)f2bf(f0.y);
      Bs[bn +  2][bk] = (short)f2bf(f0.z);
      Bs[bn +  3][bk] = (short)f2bf(f0.w);
      Bs[bn +  4][bk] = (short)f2bf(f1.x);
      Bs[bn +  5][bk] = (short)f2bf(f1.y);
      Bs[bn +  6][bk] = (short)f2bf(f1.z);
      Bs[bn +  7][bk] = (short)f2bf(f1.w);
      Bs[bn +  8][bk] = (short)f2bf(f2.x);
      Bs[bn +  9][bk] = (short)f2bf(f2.y);
      Bs[bn + 10][bk] = (short)f2bf(f2.z);
      Bs[bn + 11][bk] = (short)f2bf(f2.w);
      Bs[bn + 12][bk] = (short)f2bf(f3.x);
      Bs[bn + 13][bk] = (short)f2bf(f3.y);
      Bs[bn + 14][bk] = (short)f2bf(f3.z);
      Bs[bn + 15][bk] = (short)f2bf(f3.w);
    }
    __syncthreads();

    short8v b0 = *(const short8v*)&Bs[w * 32 + lc16][g * 8];
    short8v b1 = *(const short8v*)&Bs[w * 32 + 16 + lc16][g * 8];
#pragma unroll
    for (int mt = 0; mt < 4; ++mt) {
      short8v a = *(const short8v*)&As[mt * 16 + lc16][g * 8];
      acc[mt][0] = __builtin_amdgcn_mfma_f32_16x16x32_bf16(a, b0, acc[mt][0], 0, 0, 0);
      acc[mt][1] = __builtin_amdgcn_mfma_f32_16x16x32_bf16(a, b1, acc[mt][1], 0, 0, 0);
    }
    __syncthreads();
  }

#pragma unroll
  for (int nt = 0; nt < 2; ++nt) {
    const int ocol = col0 + w * 32 + nt * 16 + lc16;
    const float bb = bias[ocol];
#pragma unroll
    for (int mt = 0; mt < 4; ++mt)
#pragma unroll
      for (int r = 0; r < 4; ++r) {
        const int orow = row0 + mt * 16 + g * 4 + r;
        const float val = acc[mt][nt][r] + bb;
        if (mode == 0) {
          Cf[(size_t)orow * TD + ocol] = val;
        } else {
          const int bI = orow >> 11, s = orow & 2047;
          const int hI = ocol >> 6, dh = ocol & 63;
          Cbf[(((size_t)(bI * TH + hI) * TS + s) * TDH) + dh] = (short)f2bf(val);
        }
      }
  }
}

// ---------------------------------------------------------------------------
// gemm_v: V projection (N=64), old proven 64x64 structure.
// ---------------------------------------------------------------------------
__global__ __launch_bounds__(256) void gemm_v(
    const float* __restrict__ x, const float* __restrict__ Wv,
    const float* __restrict__ bv, float* __restrict__ Vb)
{
  __shared__ short As[64][40];
  __shared__ short Bs[64][40];

  const int tid  = threadIdx.x;
  const int w    = tid >> 6;
  const int lane = tid & 63;
  const int g    = lane >> 4;
  const int lc16 = lane & 15;
  const int wm   = w >> 1;
  const int wn   = w & 1;
  const int row0 = blockIdx.x * 64;

  const int ar = tid >> 2;
  const int ak = (tid & 3) << 3;
  const int wk = tid >> 3;
  const int wn8 = (tid & 7) << 3;

  f32x4 acc[2][2];
#pragma unroll
  for (int i = 0; i < 2; ++i)
#pragma unroll
    for (int j = 0; j < 2; ++j) acc[i][j] = (f32x4){0.f, 0.f, 0.f, 0.f};

  for (int kt = 0; kt < TD; kt += 32) {
    {
      const float* ap = x + (size_t)(row0 + ar) * TD + kt + ak;
      float4 f0 = *(const float4*)ap;
      float4 f1 = *(const float4*)(ap + 4);
      short8v v;
      v[0] = (short)f2bf(f0.x); v[1] = (short)f2bf(f0.y);
      v[2] = (short)f2bf(f0.z); v[3] = (short)f2bf(f0.w);
      v[4] = (short)f2bf(f1.x); v[5] = (short)f2bf(f1.y);
      v[6] = (short)f2bf(f1.z); v[7] = (short)f2bf(f1.w);
      *(short8v*)&As[ar][ak] = v;
    }
    if (wn8 < TDH) {
      const float* wp = Wv + (size_t)(kt + wk) * TDH + wn8;
      float4 f0 = *(const float4*)wp;
      float4 f1 = *(const float4*)(wp + 4);
      Bs[wn8 + 0][wk] = (short)f2bf(f0.x);
      Bs[wn8 + 1][wk] = (short)f2bf(f0.y);
      Bs[wn8 + 2][wk] = (short)f2bf(f0.z);
      Bs[wn8 + 3][wk] = (short)f2bf(f0.w);
      Bs[wn8 + 4][wk] = (short)f2bf(f1.x);
      Bs[wn8 + 5][wk] = (short)f2bf(f1.y);
      Bs[wn8 + 6][wk] = (short)f2bf(f1.z);
      Bs[wn8 + 7][wk] = (short)f2bf(f1.w);
    }
    __syncthreads();

    short8v a0 = *(const short8v*)&As[wm * 32 + lc16][g * 8];
    short8v a1 = *(const short8v*)&As[wm * 32 + 16 + lc16][g * 8];
    short8v b0 = *(const short8v*)&Bs[wn * 32 + lc16][g * 8];
    short8v b1 = *(const short8v*)&Bs[wn * 32 + 16 + lc16][g * 8];
    acc[0][0] = __builtin_amdgcn_mfma_f32_16x16x32_bf16(a0, b0, acc[0][0], 0, 0, 0);
    acc[0][1] = __builtin_amdgcn_mfma_f32_16x16x32_bf16(a0, b1, acc[0][1], 0, 0, 0);
    acc[1][0] = __builtin_amdgcn_mfma_f32_16x16x32_bf16(a1, b0, acc[1][0], 0, 0, 0);
    acc[1][1] = __builtin_amdgcn_mfma_f32_16x16x32_bf16(a1, b1, acc[1][1], 0, 0, 0);
    __syncthreads();
  }

  if (wn == 0) {   // only cols 0..63 valid
#pragma unroll
    for (int ni = 0; ni < 2; ++ni) {
      const int ocol = ni * 16 + lc16;
      const float bb = bv[ocol];
#pragma unroll
      for (int mi = 0; mi < 2; ++mi)
#pragma unroll
        for (int r = 0; r < 4; ++r) {
          const int orow = row0 + wm * 32 + mi * 16 + g * 4 + r;
          Vb[(size_t)orow * TDH + ocol] = acc[mi][ni][r] + bb;
        }
    }
  } else if (wn == 1 && wm == 0) {
    // waves 1,3 computed cols 32..63 into their acc? No: wn==1 covers cols
    // 32..63 region of the 64-wide tile -> also valid. Write them.
#pragma unroll
    for (int ni = 0; ni < 2; ++ni) {
      const int ocol = 32 + ni * 16 + lc16;
      const float bb = bv[ocol];
#pragma unroll
      for (int mi = 0; mi < 2; ++mi)
#pragma unroll
        for (int r = 0; r < 4; ++r) {
          const int orow = row0 + mi * 16 + g * 4 + r;
          Vb[(size_t)orow * TDH + ocol] = acc[mi][ni][r] + bb;
        }
    }
  } else if (wn == 1 && wm == 1) {
#pragma unroll
    for (int ni = 0; ni < 2; ++ni) {
      const int ocol = 32 + ni * 16 + lc16;
      const float bb = bv[ocol];
#pragma unroll
      for (int mi = 0; mi < 2; ++mi)
#pragma unroll
        for (int r = 0; r < 4; ++r) {
          const int orow = row0 + 32 + mi * 16 + g * 4 + r;
          Vb[(size_t)orow * TDH + ocol] = acc[mi][ni][r] + bb;
        }
    }
  }
}

// ---------------------------------------------------------------------------
// zgemm (R8/R10 structure, fp16 output): Z[q][j] = Q.K^T. Register NT-GEMM,
// no LDS/barriers. Block = 64q x 256j, one head. mfma(K,Q): D col = q,
// row = j -> lane's 4 acc values are 4 consecutive j -> one 8B fp16 store.
// ---------------------------------------------------------------------------
__global__ __launch_bounds__(256) void zgemm(
    const short* __restrict__ Qh, const short* __restrict__ Kh,
    _Float16* __restrict__ Zh, int bsel, int q0s, int qc)
{
  const int tid  = threadIdx.x;
  const int w    = tid >> 6;
  const int lane = tid & 63;
  const int g    = lane >> 4;
  const int lc16 = lane & 15;
  const int h    = blockIdx.z;
  const int pair = bsel * TH + h;
  const int jb   = blockIdx.x * 256 + w * 64;
  const int qlb  = blockIdx.y * 64;
  const int qb   = q0s + qlb;

  const short* Qp = Qh + (size_t)pair * TS * TDH;
  const short* Kp = Kh + (size_t)pair * TS * TDH;

  short8v bq[4][2];
#pragma unroll
  for (int ct = 0; ct < 4; ++ct) {
    const short* qp = Qp + (size_t)(qb + ct * 16 + lc16) * TDH + g * 8;
    bq[ct][0] = *(const short8v*)qp;
    bq[ct][1] = *(const short8v*)(qp + 32);
  }

  f32x4 acc[4][4];
#pragma unroll
  for (int rt = 0; rt < 4; ++rt)
#pragma unroll
    for (int ct = 0; ct < 4; ++ct) acc[rt][ct] = (f32x4){0.f, 0.f, 0.f, 0.f};

#pragma unroll
  for (int rt = 0; rt < 4; ++rt) {
    const short* kp = Kp + (size_t)(jb + rt * 16 + lc16) * TDH + g * 8;
    short8v ak0 = *(const short8v*)kp;
    short8v ak1 = *(const short8v*)(kp + 32);
#pragma unroll
    for (int ct = 0; ct < 4; ++ct) {
      acc[rt][ct] = __builtin_amdgcn_mfma_f32_16x16x32_bf16(ak0, bq[ct][0], acc[rt][ct], 0, 0, 0);
      acc[rt][ct] = __builtin_amdgcn_mfma_f32_16x16x32_bf16(ak1, bq[ct][1], acc[rt][ct], 0, 0, 0);
    }
  }

#pragma unroll
  for (int rt = 0; rt < 4; ++rt)
#pragma unroll
    for (int ct = 0; ct < 4; ++ct) {
      half4v o = {(_Float16)acc[rt][ct][0], (_Float16)acc[rt][ct][1],
                  (_Float16)acc[rt][ct][2], (_Float16)acc[rt][ct][3]};
      *(half4v*)&Zh[((size_t)h * qc + qlb + ct * 16 + lc16) * TS + jb + rt * 16 + g * 4] = o;
    }
}

// ---------------------------------------------------------------------------
// spv (R11 structure, fp16 input): one block per (b,q), 512 thr = 8 waves,
// wave = head. Row = 4 x half8 per lane (j = k*512 + lane*8 + c), converted
// to f32 regs. Max -> tau0 = zmax-1 -> <=4 candidates/lane in named regs ->
// 4-reg Michelot (dense fallback if lane overflow) -> support scatter to LDS
// avg row + PV list -> batched sparse PV -> heads; one dense avg write.
// ---------------------------------------------------------------------------
__global__ __launch_bounds__(512) void spv(
    const _Float16* __restrict__ Zh, const float* __restrict__ V,
    short* __restrict__ heads, float* __restrict__ avg,
    int bsel, int q0s, int qc)
{
  __shared__ float avgS[TS];                 // 8 KB
  __shared__ unsigned short idxW[TH][CAP];   // 4 KB
  __shared__ float pW[TH][CAP];              // 8 KB
  __shared__ int cntW[TH];

  const int tid  = threadIdx.x;
  const int h    = tid >> 6;                 // wave = head
  const int lane = tid & 63;
  const int ql   = blockIdx.x;
  const int q    = q0s + ql;
  const int row  = bsel * TS + q;
  const float* Vb = V + (size_t)bsel * TS * TDH;

  *(f32x4*)&avgS[(tid << 2) & (TS - 1)] = (f32x4){0.f, 0.f, 0.f, 0.f};
  if (lane == 0) cntW[h] = 0;
  __syncthreads();

  // ---- load row (fp16) and convert to f32 regs ----
  float za[4][8];
  const _Float16* zp = Zh + ((size_t)h * qc + ql) * TS;
#pragma unroll
  for (int k = 0; k < 4; ++k) {
    half8v v = *(const half8v*)(zp + (k << 9) + (lane << 3));
#pragma unroll
    for (int c = 0; c < 8; ++c) za[k][c] = (float)v[c];
  }

  // ---- wave row max ----
  float m = za[0][0];
#pragma unroll
  for (int k = 0; k < 4; ++k)
#pragma unroll
    for (int c = 0; c < 8; ++c) m = fmaxf(m, za[k][c]);
#pragma unroll
  for (int s = 1; s < 64; s <<= 1) m = fmaxf(m, __shfl_xor(m, s));
  const float tau0 = m - 1.0f;

  // ---- extract <=4 candidates per lane (named regs) ----
  float c0 = -1e30f, c1 = -1e30f, c2 = -1e30f, c3 = -1e30f;
  int j0 = 0, j1 = 0, j2 = 0, j3 = 0, nc = 0;
#pragma unroll
  for (int k = 0; k < 4; ++k)
#pragma unroll
    for (int c = 0; c < 8; ++c) {
      const float v = za[k][c];
      if (v > tau0) {
        c3 = c2; j3 = j2; c2 = c1; j2 = j1; c1 = c0; j1 = j0;
        c0 = v; j0 = (k << 9) + (lane << 3) + c; ++nc;
      }
    }
  const bool over = (__ballot(nc > 4) != 0ull);

  // ---- Michelot fixpoint (exact tau) ----
  float tau = tau0;
  int prevc = -1;
  if (!over) {
    for (int it = 0; it < 64; ++it) {
      float s = 0.f, c = 0.f;
      if (c0 > tau) { s += c0; c += 1.f; }
      if (c1 > tau) { s += c1; c += 1.f; }
      if (c2 > tau) { s += c2; c += 1.f; }
      if (c3 > tau) { s += c3; c += 1.f; }
#pragma unroll
      for (int sh = 1; sh < 64; sh <<= 1) {
        s += __shfl_xor(s, sh);
        c += __shfl_xor(c, sh);
      }
      tau = (s - 1.f) / c;
      const int ci = (int)c;
      if (ci == prevc) break;
      prevc = ci;
    }
  } else {
    for (int it = 0; it < 64; ++it) {
      float s = 0.f, c = 0.f;
#pragma unroll
      for (int k = 0; k < 4; ++k)
#pragma unroll
        for (int cc = 0; cc < 8; ++cc) {
          const float v = za[k][cc];
          if (v > tau) { s += v; c += 1.f; }
        }
#pragma unroll
      for (int sh = 1; sh < 64; sh <<= 1) {
        s += __shfl_xor(s, sh);
        c += __shfl_xor(c, sh);
      }
      tau = (s - 1.f) / c;
      const int ci = (int)c;
      if (ci == prevc) break;
      prevc = ci;
    }
  }

  // ---- emit support: avg scatter + PV list ----
  if (!over) {
    {
      const float p = c0 - tau;
      if (p > 0.f) {
        atomicAdd(&avgS[j0], p);
        const int pos = atomicAdd(&cntW[h], 1);
        if (pos < CAP) { idxW[h][pos] = (unsigned short)j0; pW[h][pos] = p; }
      }
    }
    {
      const float p = c1 - tau;
      if (p > 0.f) {
        atomicAdd(&avgS[j1], p);
        const int pos = atomicAdd(&cntW[h], 1);
        if (pos < CAP) { idxW[h][pos] = (unsigned short)j1; pW[h][pos] = p; }
      }
    }
    {
      const float p = c2 - tau;
      if (p > 0.f) {
        atomicAdd(&avgS[j2], p);
        const int pos = atomicAdd(&cntW[h], 1);
        if (pos < CAP) { idxW[h][pos] = (unsigned short)j2; pW[h][pos] = p; }
      }
    }
    {
      const float p = c3 - tau;
      if (p > 0.f) {
        atomicAdd(&avgS[j3], p);
        const int pos = atomicAdd(&cntW[h], 1);
        if (pos < CAP) { idxW[h][pos] = (unsigned short)j3; pW[h][pos] = p; }
      }
    }
  } else {
#pragma unroll
    for (int k = 0; k < 4; ++k)
#pragma unroll
      for (int cc = 0; cc < 8; ++cc) {
        const float p = za[k][cc] - tau;
        if (p > 0.f) {
          const int j = (k << 9) + (lane << 3) + cc;
          atomicAdd(&avgS[j], p);
          const int pos = atomicAdd(&cntW[h], 1);
          if (pos < CAP) { idxW[h][pos] = (unsigned short)j; pW[h][pos] = p; }
        }
      }
  }

  // ---- PV (wave-local list; cnt visible in program order) ----
  const int cnt = cntW[h];
  float a = 0.f;
  if (cnt <= CAP) {
    for (int e0 = 0; e0 < cnt; e0 += 8) {
      float pb[8], vb8[8];
#pragma unroll
      for (int u = 0; u < 8; ++u) {
        const int e = e0 + u;
        const int ec = (e < cnt) ? e : 0;
        pb[u] = (e < cnt) ? pW[h][ec] : 0.f;
        vb8[u] = Vb[(size_t)idxW[h][ec] * TDH + lane];
      }
#pragma unroll
      for (int u = 0; u < 8; ++u) a += pb[u] * vb8[u];
    }
  } else {
    // ballot-serial dense fallback (support > CAP; essentially never)
#pragma unroll
    for (int k = 0; k < 4; ++k)
#pragma unroll
      for (int cc = 0; cc < 8; ++cc) {
        const float p = za[k][cc] - tau;
        unsigned long long mask = __ballot(p > 0.f);
        while (mask) {
          const int src = __ffsll((long long)mask) - 1;
          mask &= mask - 1;
          const float pj = __shfl(p, src);
          const int j = (k << 9) + (src << 3) + cc;
          a += pj * Vb[(size_t)j * TDH + lane];
        }
      }
  }
  heads[(size_t)row * TD + h * TDH + lane] = (short)f2bf(a);

  // ---- dense avg write ----
  __syncthreads();
  {
    f32x4 t = *(const f32x4*)&avgS[(tid << 2) & (TS - 1)];
    if (tid < 512) {
      float4 o = {t[0] * 0.125f, t[1] * 0.125f, t[2] * 0.125f, t[3] * 0.125f};
      *(float4*)(avg + (size_t)row * TS + (tid << 2)) = o;
    }
  }
}

// ---------------------------------------------------------------------------
extern "C" void kernel_launch(void* const* d_in, const int* in_sizes, int n_in,
                              void* d_out, int out_size, void* d_ws, size_t ws_size,
                              hipStream_t stream) {
  (void)in_sizes; (void)n_in; (void)out_size;

  const float* x    = (const float*)d_in[0];
  const float* Wq   = (const float*)d_in[1];
  const float* bq   = (const float*)d_in[2];
  const float* Wk   = (const float*)d_in[3];
  const float* bk   = (const float*)d_in[4];
  const float* Wv   = (const float*)d_in[5];
  const float* bv   = (const float*)d_in[6];
  const float* Wout = (const float*)d_in[7];
  const float* bout = (const float*)d_in[8];

  float* out   = (float*)d_out;
  float* x_out = out;                       // [2,2048,512]
  float* avg   = out + 2097152;             // [2,2048,2048]

  float* ws = (float*)d_ws;
  float* Vb = ws;                           // f32 [2][2048][64]   (262144 fl)
  short* Hd = (short*)(ws + 262144);        // bf16 [4096][512]    (1048576 fl)
  short* Qh = (short*)(ws + 1310720);       // bf16 [16][2048][64] (1048576 fl)
  short* Kh = (short*)(ws + 2359296);       // bf16 [16][2048][64] (1048576 fl)
  _Float16* Zh = (_Float16*)(ws + 3407872); // fp16 slab [8][qc][2048]

  // largest q-chunk that fits the workspace (fp16 slab = qc*TH*TS/2 floats)
  const size_t wsFloats = ws_size / 4;
  const size_t base = 3407872;
  int qc = 64;
  for (int cand = 2048; cand >= 64; cand >>= 1) {
    if (base + (size_t)TH * cand * TS / 2 <= wsFloats) { qc = cand; break; }
  }

  const dim3 blk(256);
  const int BS = 2 * TS;                    // 4096 rows

  // projections
  gemm128<<<dim3(BS / 64, TD / 128), blk, 0, stream>>>(x, 0, Wq, bq, nullptr, Qh, 1);
  gemm128<<<dim3(BS / 64, TD / 128), blk, 0, stream>>>(x, 0, Wk, bk, nullptr, Kh, 1);
  gemm_v<<<dim3(BS / 64), blk, 0, stream>>>(x, Wv, bv, Vb);

  // attention, slabbed over (batch, q-chunk)
  for (int bsel = 0; bsel < 2; ++bsel)
    for (int q0s = 0; q0s < TS; q0s += qc) {
      zgemm<<<dim3(TS / 256, qc / 64, TH), blk, 0, stream>>>(Qh, Kh, Zh, bsel, q0s, qc);
      spv<<<dim3(qc), dim3(512), 0, stream>>>(Zh, Vb, Hd, avg, bsel, q0s, qc);
    }

  // output projection
  gemm128<<<dim3(BS / 64, TD / 128), blk, 0, stream>>>(Hd, 1, Wout, bout, x_out, nullptr, 0);
}

// Round 13
// 164.664 us; speedup vs baseline: 1.2196x; 1.2196x over previous
//
#include <hip/hip_runtime.h>
#include <cstddef>
#include <cstdint>

#define TS 2048   // sequence length S
#define TD 512    // model dim D
#define TH 8      // heads
#define TDH 64    // head dim
#define CAP 256   // support entries per head list (ballot fallback beyond)

typedef float f32x4 __attribute__((ext_vector_type(4)));
typedef short short8v __attribute__((ext_vector_type(8)));
typedef _Float16 half4v __attribute__((ext_vector_type(4)));
typedef _Float16 half8v __attribute__((ext_vector_type(8)));

__device__ __forceinline__ unsigned short f2bf(float f) {
  unsigned u = __builtin_bit_cast(unsigned, f);
  u += 0x7fff + ((u >> 16) & 1);          // RNE
  return (unsigned short)(u >> 16);
}

// ---------------------------------------------------------------------------
// Fused QKV projection (proven R9-R11): one launch, W selected per blockIdx.y.
// by 0..7 -> Wq (bf16 head-major Qh), 8..15 -> Wk (-> Kh), 16 -> Wv (f32 Vb).
// ---------------------------------------------------------------------------
__global__ __launch_bounds__(256) void proj_gemm(
    const float* __restrict__ x,
    const float* __restrict__ Wq, const float* __restrict__ bq,
    const float* __restrict__ Wk, const float* __restrict__ bk,
    const float* __restrict__ Wv, const float* __restrict__ bv,
    short* __restrict__ Qh, short* __restrict__ Kh, float* __restrict__ Vb)
{
  __shared__ short As[64][40];
  __shared__ short Bs[64][40];

  const int by = blockIdx.y;
  const float* W; const float* bias; int N; int col0; int outsel;
  if (by < 8)       { W = Wq; bias = bq; N = TD;  col0 = by * 64;       outsel = 0; }
  else if (by < 16) { W = Wk; bias = bk; N = TD;  col0 = (by - 8) * 64; outsel = 1; }
  else              { W = Wv; bias = bv; N = TDH; col0 = 0;             outsel = 2; }

  const int tid  = threadIdx.x;
  const int w    = tid >> 6;
  const int lane = tid & 63;
  const int g    = lane >> 4;
  const int lc16 = lane & 15;
  const int wm   = w >> 1;
  const int wn   = w & 1;
  const int row0 = blockIdx.x * 64;

  const int ar = tid >> 2;
  const int ak = (tid & 3) << 3;
  const int wk = tid >> 3;
  const int wn8 = (tid & 7) << 3;

  f32x4 acc[2][2];
#pragma unroll
  for (int i = 0; i < 2; ++i)
#pragma unroll
    for (int j = 0; j < 2; ++j) acc[i][j] = (f32x4){0.f, 0.f, 0.f, 0.f};

  for (int kt = 0; kt < TD; kt += 32) {
    {
      const float* ap = x + (size_t)(row0 + ar) * TD + kt + ak;
      float4 f0 = *(const float4*)ap;
      float4 f1 = *(const float4*)(ap + 4);
      short8v v;
      v[0] = (short)f2bf(f0.x); v[1] = (short)f2bf(f0.y);
      v[2] = (short)f2bf(f0.z); v[3] = (short)f2bf(f0.w);
      v[4] = (short)f2bf(f1.x); v[5] = (short)f2bf(f1.y);
      v[6] = (short)f2bf(f1.z); v[7] = (short)f2bf(f1.w);
      *(short8v*)&As[ar][ak] = v;
    }
    {
      const float* wp = W + (size_t)(kt + wk) * N + col0 + wn8;
      float4 f0 = *(const float4*)wp;
      float4 f1 = *(const float4*)(wp + 4);
      Bs[wn8 + 0][wk] = (short)f2bf(f0.x);
      Bs[wn8 + 1][wk] = (short)f2bf(f0.y);
      Bs[wn8 + 2][wk] = (short)f2bf(f0.z);
      Bs[wn8 + 3][wk] = (short)f2bf(f0.w);
      Bs[wn8 + 4][wk] = (short)f2bf(f1.x);
      Bs[wn8 + 5][wk] = (short)f2bf(f1.y);
      Bs[wn8 + 6][wk] = (short)f2bf(f1.z);
      Bs[wn8 + 7][wk] = (short)f2bf(f1.w);
    }
    __syncthreads();

    short8v a0 = *(const short8v*)&As[wm * 32 + lc16][g * 8];
    short8v a1 = *(const short8v*)&As[wm * 32 + 16 + lc16][g * 8];
    short8v b0 = *(const short8v*)&Bs[wn * 32 + lc16][g * 8];
    short8v b1 = *(const short8v*)&Bs[wn * 32 + 16 + lc16][g * 8];
    acc[0][0] = __builtin_amdgcn_mfma_f32_16x16x32_bf16(a0, b0, acc[0][0], 0, 0, 0);
    acc[0][1] = __builtin_amdgcn_mfma_f32_16x16x32_bf16(a0, b1, acc[0][1], 0, 0, 0);
    acc[1][0] = __builtin_amdgcn_mfma_f32_16x16x32_bf16(a1, b0, acc[1][0], 0, 0, 0);
    acc[1][1] = __builtin_amdgcn_mfma_f32_16x16x32_bf16(a1, b1, acc[1][1], 0, 0, 0);
    __syncthreads();
  }

  short* Obf = (outsel == 0) ? Qh : Kh;
#pragma unroll
  for (int ni = 0; ni < 2; ++ni) {
    const int ocol = col0 + wn * 32 + ni * 16 + lc16;
    if (ocol >= N) continue;
    const float bb = bias[ocol];
#pragma unroll
    for (int mi = 0; mi < 2; ++mi)
#pragma unroll
      for (int r = 0; r < 4; ++r) {
        const int orow = row0 + wm * 32 + mi * 16 + g * 4 + r;
        const float val = acc[mi][ni][r] + bb;
        if (outsel == 2) {
          Vb[(size_t)orow * TDH + ocol] = val;
        } else {
          const int bI = orow >> 11, s = orow & 2047;
          const int hI = ocol >> 6, dh = ocol & 63;
          Obf[(((size_t)(bI * TH + hI) * TS + s) * TDH) + dh] = (short)f2bf(val);
        }
      }
  }
}

// ---------------------------------------------------------------------------
// Output projection GEMM (proven): x_out = Hd(bf16) @ Wout + bout.
// ---------------------------------------------------------------------------
__global__ __launch_bounds__(256) void gemm_out(
    const short* __restrict__ A, const float* __restrict__ W,
    const float* __restrict__ bias, float* __restrict__ Cf, int N, int Kd)
{
  __shared__ short As[64][40];
  __shared__ short Bs[64][40];

  const int tid  = threadIdx.x;
  const int w    = tid >> 6;
  const int lane = tid & 63;
  const int g    = lane >> 4;
  const int lc16 = lane & 15;
  const int wm   = w >> 1;
  const int wn   = w & 1;
  const int row0 = blockIdx.x * 64;
  const int col0 = blockIdx.y * 64;

  const int ar = tid >> 2;
  const int ak = (tid & 3) << 3;
  const int wk = tid >> 3;
  const int wn8 = (tid & 7) << 3;

  f32x4 acc[2][2];
#pragma unroll
  for (int i = 0; i < 2; ++i)
#pragma unroll
    for (int j = 0; j < 2; ++j) acc[i][j] = (f32x4){0.f, 0.f, 0.f, 0.f};

  for (int kt = 0; kt < Kd; kt += 32) {
    {
      short8v v = *(const short8v*)(A + (size_t)(row0 + ar) * Kd + kt + ak);
      *(short8v*)&As[ar][ak] = v;
    }
    {
      const float* wp = W + (size_t)(kt + wk) * N + col0 + wn8;
      float4 f0 = *(const float4*)wp;
      float4 f1 = *(const float4*)(wp + 4);
      Bs[wn8 + 0][wk] = (short)f2bf(f0.x);
      Bs[wn8 + 1][wk] = (short)f2bf(f0.y);
      Bs[wn8 + 2][wk] = (short)f2bf(f0.z);
      Bs[wn8 + 3][wk] = (short)f2bf(f0.w);
      Bs[wn8 + 4][wk] = (short)f2bf(f1.x);
      Bs[wn8 + 5][wk] = (short)f2bf(f1.y);
      Bs[wn8 + 6][wk] = (short)f2bf(f1.z);
      Bs[wn8 + 7][wk] = (short)f2bf(f1.w);
    }
    __syncthreads();

    short8v a0 = *(const short8v*)&As[wm * 32 + lc16][g * 8];
    short8v a1 = *(const short8v*)&As[wm * 32 + 16 + lc16][g * 8];
    short8v b0 = *(const short8v*)&Bs[wn * 32 + lc16][g * 8];
    short8v b1 = *(const short8v*)&Bs[wn * 32 + 16 + lc16][g * 8];
    acc[0][0] = __builtin_amdgcn_mfma_f32_16x16x32_bf16(a0, b0, acc[0][0], 0, 0, 0);
    acc[0][1] = __builtin_amdgcn_mfma_f32_16x16x32_bf16(a0, b1, acc[0][1], 0, 0, 0);
    acc[1][0] = __builtin_amdgcn_mfma_f32_16x16x32_bf16(a1, b0, acc[1][0], 0, 0, 0);
    acc[1][1] = __builtin_amdgcn_mfma_f32_16x16x32_bf16(a1, b1, acc[1][1], 0, 0, 0);
    __syncthreads();
  }

#pragma unroll
  for (int ni = 0; ni < 2; ++ni) {
    const int ocol = col0 + wn * 32 + ni * 16 + lc16;
    const float bb = bias[ocol];
#pragma unroll
    for (int mi = 0; mi < 2; ++mi)
#pragma unroll
      for (int r = 0; r < 4; ++r) {
        const int orow = row0 + wm * 32 + mi * 16 + g * 4 + r;
        Cf[(size_t)orow * N + ocol] = acc[mi][ni][r] + bb;
      }
  }
}

// ---------------------------------------------------------------------------
// zgemm (R8/R10 structure; fp16 output is the ONLY change vs R11):
// Z[q][j] = Q.K^T. Register NT-GEMM, no LDS/barriers. Block = 64q x 256j,
// one head. mfma(K,Q): D col = q, row = j -> lane's 4 acc values are 4
// consecutive j -> one 8B fp16 store.
// ---------------------------------------------------------------------------
__global__ __launch_bounds__(256) void zgemm(
    const short* __restrict__ Qh, const short* __restrict__ Kh,
    _Float16* __restrict__ Zh, int bsel, int q0s, int qc)
{
  const int tid  = threadIdx.x;
  const int w    = tid >> 6;
  const int lane = tid & 63;
  const int g    = lane >> 4;
  const int lc16 = lane & 15;
  const int h    = blockIdx.z;
  const int pair = bsel * TH + h;
  const int jb   = blockIdx.x * 256 + w * 64;
  const int qlb  = blockIdx.y * 64;
  const int qb   = q0s + qlb;

  const short* Qp = Qh + (size_t)pair * TS * TDH;
  const short* Kp = Kh + (size_t)pair * TS * TDH;

  short8v bq[4][2];
#pragma unroll
  for (int ct = 0; ct < 4; ++ct) {
    const short* qp = Qp + (size_t)(qb + ct * 16 + lc16) * TDH + g * 8;
    bq[ct][0] = *(const short8v*)qp;
    bq[ct][1] = *(const short8v*)(qp + 32);
  }

  f32x4 acc[4][4];
#pragma unroll
  for (int rt = 0; rt < 4; ++rt)
#pragma unroll
    for (int ct = 0; ct < 4; ++ct) acc[rt][ct] = (f32x4){0.f, 0.f, 0.f, 0.f};

#pragma unroll
  for (int rt = 0; rt < 4; ++rt) {
    const short* kp = Kp + (size_t)(jb + rt * 16 + lc16) * TDH + g * 8;
    short8v ak0 = *(const short8v*)kp;
    short8v ak1 = *(const short8v*)(kp + 32);
#pragma unroll
    for (int ct = 0; ct < 4; ++ct) {
      acc[rt][ct] = __builtin_amdgcn_mfma_f32_16x16x32_bf16(ak0, bq[ct][0], acc[rt][ct], 0, 0, 0);
      acc[rt][ct] = __builtin_amdgcn_mfma_f32_16x16x32_bf16(ak1, bq[ct][1], acc[rt][ct], 0, 0, 0);
    }
  }

#pragma unroll
  for (int rt = 0; rt < 4; ++rt)
#pragma unroll
    for (int ct = 0; ct < 4; ++ct) {
      half4v o = {(_Float16)acc[rt][ct][0], (_Float16)acc[rt][ct][1],
                  (_Float16)acc[rt][ct][2], (_Float16)acc[rt][ct][3]};
      *(half4v*)&Zh[((size_t)h * qc + qlb + ct * 16 + lc16) * TS + jb + rt * 16 + g * 4] = o;
    }
}

// ---------------------------------------------------------------------------
// spv (R11 structure; fp16 input is the ONLY change): one block per (b,q),
// 512 thr = 8 waves, wave = head. Row = 4 x half8 per lane (j = k*512 +
// lane*8 + c), converted to f32 regs. Max -> tau0 = zmax-1 -> <=4 candidates
// per lane in NAMED regs -> 4-reg Michelot (dense fallback on lane overflow)
// -> support scatter to LDS avg row + PV list -> batched sparse PV -> heads;
// one dense avg write.
// ---------------------------------------------------------------------------
__global__ __launch_bounds__(512) void spv(
    const _Float16* __restrict__ Zh, const float* __restrict__ V,
    short* __restrict__ heads, float* __restrict__ avg,
    int bsel, int q0s, int qc)
{
  __shared__ float avgS[TS];                 // 8 KB
  __shared__ unsigned short idxW[TH][CAP];   // 4 KB
  __shared__ float pW[TH][CAP];              // 8 KB
  __shared__ int cntW[TH];

  const int tid  = threadIdx.x;
  const int h    = tid >> 6;                 // wave = head
  const int lane = tid & 63;
  const int ql   = blockIdx.x;
  const int q    = q0s + ql;
  const int row  = bsel * TS + q;
  const float* Vb = V + (size_t)bsel * TS * TDH;

  *(f32x4*)&avgS[tid << 2] = (f32x4){0.f, 0.f, 0.f, 0.f};
  if (lane == 0) cntW[h] = 0;
  __syncthreads();

  // ---- load row (fp16) and convert to f32 regs ----
  float za[4][8];
  const _Float16* zp = Zh + ((size_t)h * qc + ql) * TS;
#pragma unroll
  for (int k = 0; k < 4; ++k) {
    half8v v = *(const half8v*)(zp + (k << 9) + (lane << 3));
#pragma unroll
    for (int c = 0; c < 8; ++c) za[k][c] = (float)v[c];
  }

  // ---- wave row max ----
  float m = za[0][0];
#pragma unroll
  for (int k = 0; k < 4; ++k)
#pragma unroll
    for (int c = 0; c < 8; ++c) m = fmaxf(m, za[k][c]);
#pragma unroll
  for (int s = 1; s < 64; s <<= 1) m = fmaxf(m, __shfl_xor(m, s));
  const float tau0 = m - 1.0f;

  // ---- extract <=4 candidates per lane (named regs, static indexing) ----
  float c0 = -1e30f, c1 = -1e30f, c2 = -1e30f, c3 = -1e30f;
  int j0 = 0, j1 = 0, j2 = 0, j3 = 0, nc = 0;
#pragma unroll
  for (int k = 0; k < 4; ++k)
#pragma unroll
    for (int c = 0; c < 8; ++c) {
      const float v = za[k][c];
      if (v > tau0) {
        c3 = c2; j3 = j2; c2 = c1; j2 = j1; c1 = c0; j1 = j0;
        c0 = v; j0 = (k << 9) + (lane << 3) + c; ++nc;
      }
    }
  const bool over = (__ballot(nc > 4) != 0ull);

  // ---- Michelot fixpoint (exact tau) ----
  float tau = tau0;
  int prevc = -1;
  if (!over) {
    for (int it = 0; it < 64; ++it) {
      float s = 0.f, c = 0.f;
      if (c0 > tau) { s += c0; c += 1.f; }
      if (c1 > tau) { s += c1; c += 1.f; }
      if (c2 > tau) { s += c2; c += 1.f; }
      if (c3 > tau) { s += c3; c += 1.f; }
#pragma unroll
      for (int sh = 1; sh < 64; sh <<= 1) {
        s += __shfl_xor(s, sh);
        c += __shfl_xor(c, sh);
      }
      tau = (s - 1.f) / c;
      const int ci = (int)c;
      if (ci == prevc) break;
      prevc = ci;
    }
  } else {
    for (int it = 0; it < 64; ++it) {
      float s = 0.f, c = 0.f;
#pragma unroll
      for (int k = 0; k < 4; ++k)
#pragma unroll
        for (int cc = 0; cc < 8; ++cc) {
          const float v = za[k][cc];
          if (v > tau) { s += v; c += 1.f; }
        }
#pragma unroll
      for (int sh = 1; sh < 64; sh <<= 1) {
        s += __shfl_xor(s, sh);
        c += __shfl_xor(c, sh);
      }
      tau = (s - 1.f) / c;
      const int ci = (int)c;
      if (ci == prevc) break;
      prevc = ci;
    }
  }

  // ---- emit support: avg scatter + PV list ----
  if (!over) {
    {
      const float p = c0 - tau;
      if (p > 0.f) {
        atomicAdd(&avgS[j0], p);
        const int pos = atomicAdd(&cntW[h], 1);
        if (pos < CAP) { idxW[h][pos] = (unsigned short)j0; pW[h][pos] = p; }
      }
    }
    {
      const float p = c1 - tau;
      if (p > 0.f) {
        atomicAdd(&avgS[j1], p);
        const int pos = atomicAdd(&cntW[h], 1);
        if (pos < CAP) { idxW[h][pos] = (unsigned short)j1; pW[h][pos] = p; }
      }
    }
    {
      const float p = c2 - tau;
      if (p > 0.f) {
        atomicAdd(&avgS[j2], p);
        const int pos = atomicAdd(&cntW[h], 1);
        if (pos < CAP) { idxW[h][pos] = (unsigned short)j2; pW[h][pos] = p; }
      }
    }
    {
      const float p = c3 - tau;
      if (p > 0.f) {
        atomicAdd(&avgS[j3], p);
        const int pos = atomicAdd(&cntW[h], 1);
        if (pos < CAP) { idxW[h][pos] = (unsigned short)j3; pW[h][pos] = p; }
      }
    }
  } else {
#pragma unroll
    for (int k = 0; k < 4; ++k)
#pragma unroll
      for (int cc = 0; cc < 8; ++cc) {
        const float p = za[k][cc] - tau;
        if (p > 0.f) {
          const int j = (k << 9) + (lane << 3) + cc;
          atomicAdd(&avgS[j], p);
          const int pos = atomicAdd(&cntW[h], 1);
          if (pos < CAP) { idxW[h][pos] = (unsigned short)j; pW[h][pos] = p; }
        }
      }
  }

  // ---- PV (wave-local list; cnt visible in program order) ----
  const int cnt = cntW[h];
  float a = 0.f;
  if (cnt <= CAP) {
    for (int e0 = 0; e0 < cnt; e0 += 8) {
      float pb[8], vb8[8];
#pragma unroll
      for (int u = 0; u < 8; ++u) {
        const int e = e0 + u;
        const int ec = (e < cnt) ? e : 0;
        pb[u] = (e < cnt) ? pW[h][ec] : 0.f;
        vb8[u] = Vb[(size_t)idxW[h][ec] * TDH + lane];
      }
#pragma unroll
      for (int u = 0; u < 8; ++u) a += pb[u] * vb8[u];
    }
  } else {
    // ballot-serial dense fallback (support > CAP; essentially never)
#pragma unroll
    for (int k = 0; k < 4; ++k)
#pragma unroll
      for (int cc = 0; cc < 8; ++cc) {
        const float p = za[k][cc] - tau;
        unsigned long long mask = __ballot(p > 0.f);
        while (mask) {
          const int src = __ffsll((long long)mask) - 1;
          mask &= mask - 1;
          const float pj = __shfl(p, src);
          const int j = (k << 9) + (src << 3) + cc;
          a += pj * Vb[(size_t)j * TDH + lane];
        }
      }
  }
  heads[(size_t)row * TD + h * TDH + lane] = (short)f2bf(a);

  // ---- dense avg write ----
  __syncthreads();
  {
    f32x4 t = *(const f32x4*)&avgS[tid << 2];
    float4 o = {t[0] * 0.125f, t[1] * 0.125f, t[2] * 0.125f, t[3] * 0.125f};
    *(float4*)(avg + (size_t)row * TS + (tid << 2)) = o;
  }
}

// ---------------------------------------------------------------------------
extern "C" void kernel_launch(void* const* d_in, const int* in_sizes, int n_in,
                              void* d_out, int out_size, void* d_ws, size_t ws_size,
                              hipStream_t stream) {
  (void)in_sizes; (void)n_in; (void)out_size;

  const float* x    = (const float*)d_in[0];
  const float* Wq   = (const float*)d_in[1];
  const float* bq   = (const float*)d_in[2];
  const float* Wk   = (const float*)d_in[3];
  const float* bk   = (const float*)d_in[4];
  const float* Wv   = (const float*)d_in[5];
  const float* bv   = (const float*)d_in[6];
  const float* Wout = (const float*)d_in[7];
  const float* bout = (const float*)d_in[8];

  float* out   = (float*)d_out;
  float* x_out = out;                       // [2,2048,512]
  float* avg   = out + 2097152;             // [2,2048,2048]

  float* ws = (float*)d_ws;
  float* Vb = ws;                           // f32 [2][2048][64]   (262144 fl)
  short* Hd = (short*)(ws + 262144);        // bf16 [4096][512]    (1048576 fl)
  short* Qh = (short*)(ws + 1310720);       // bf16 [16][2048][64] (1048576 fl)
  short* Kh = (short*)(ws + 2359296);       // bf16 [16][2048][64] (1048576 fl)
  _Float16* Zh = (_Float16*)(ws + 3407872); // fp16 slab [8][qc][2048]

  // largest q-chunk that fits the workspace (fp16 slab = qc*TH*TS/2 floats)
  const size_t wsFloats = ws_size / 4;
  const size_t base = 3407872;
  int qc = 64;
  for (int cand = 2048; cand >= 64; cand >>= 1) {
    if (base + (size_t)TH * cand * TS / 2 <= wsFloats) { qc = cand; break; }
  }

  const dim3 blk(256);
  const int BS = 2 * TS;                    // 4096 rows

  // fused QKV projections (R11 structure)
  proj_gemm<<<dim3(BS / 64, 17), blk, 0, stream>>>(x, Wq, bq, Wk, bk, Wv, bv, Qh, Kh, Vb);

  // attention, slabbed over (batch, q-chunk)
  for (int bsel = 0; bsel < 2; ++bsel)
    for (int q0s = 0; q0s < TS; q0s += qc) {
      zgemm<<<dim3(TS / 256, qc / 64, TH), blk, 0, stream>>>(Qh, Kh, Zh, bsel, q0s, qc);
      spv<<<dim3(qc), dim3(512), 0, stream>>>(Zh, Vb, Hd, avg, bsel, q0s, qc);
    }

  // output projection (R11 structure)
  gemm_out<<<dim3(BS / 64, TD / 64), blk, 0, stream>>>(Hd, Wout, bout, x_out, TD, TD);
}

// Round 14
// 139.127 us; speedup vs baseline: 1.4435x; 1.1836x over previous
//
#include <hip/hip_runtime.h>
#include <cstddef>
#include <cstdint>

#define TS 2048   // sequence length S
#define TD 512    // model dim D
#define TH 8     // heads
#define TDH 64    // head dim
#define CAP 256   // support entries per head list (ballot fallback beyond)

typedef float f32x4 __attribute__((ext_vector_type(4)));
typedef short short8v __attribute__((ext_vector_type(8)));
typedef _Float16 half4v __attribute__((ext_vector_type(4)));
typedef _Float16 half8v __attribute__((ext_vector_type(8)));

__device__ __forceinline__ unsigned short f2bf(float f) {
  unsigned u = __builtin_bit_cast(unsigned, f);
  u += 0x7fff + ((u >> 16) & 1);          // RNE
  return (unsigned short)(u >> 16);
}

// ---------------------------------------------------------------------------
// cvt_bf16: x (f32) -> xb (bf16), one pass. 8 elems/thread.
// ---------------------------------------------------------------------------
__global__ __launch_bounds__(256) void cvt_bf16(
    const float* __restrict__ x, short* __restrict__ xb)
{
  const int i = (blockIdx.x * 256 + threadIdx.x) << 3;
  float4 f0 = *(const float4*)(x + i);
  float4 f1 = *(const float4*)(x + i + 4);
  short8v v;
  v[0] = (short)f2bf(f0.x); v[1] = (short)f2bf(f0.y);
  v[2] = (short)f2bf(f0.z); v[3] = (short)f2bf(f0.w);
  v[4] = (short)f2bf(f1.x); v[5] = (short)f2bf(f1.y);
  v[6] = (short)f2bf(f1.z); v[7] = (short)f2bf(f1.w);
  *(short8v*)(xb + i) = v;
}

// ---------------------------------------------------------------------------
// Fused QKV projection (R9-R13 structure; A now pre-converted bf16).
// by 0..7 -> Wq (bf16 head-major Qh), 8..15 -> Wk (-> Kh), 16 -> Wv (f32 Vb).
// ---------------------------------------------------------------------------
__global__ __launch_bounds__(256) void proj_gemm(
    const short* __restrict__ xb,
    const float* __restrict__ Wq, const float* __restrict__ bq,
    const float* __restrict__ Wk, const float* __restrict__ bk,
    const float* __restrict__ Wv, const float* __restrict__ bv,
    short* __restrict__ Qh, short* __restrict__ Kh, float* __restrict__ Vb)
{
  __shared__ short As[64][40];
  __shared__ short Bs[64][40];

  const int by = blockIdx.y;
  const float* W; const float* bias; int N; int col0; int outsel;
  if (by < 8)       { W = Wq; bias = bq; N = TD;  col0 = by * 64;       outsel = 0; }
  else if (by < 16) { W = Wk; bias = bk; N = TD;  col0 = (by - 8) * 64; outsel = 1; }
  else              { W = Wv; bias = bv; N = TDH; col0 = 0;             outsel = 2; }

  const int tid  = threadIdx.x;
  const int w    = tid >> 6;
  const int lane = tid & 63;
  const int g    = lane >> 4;
  const int lc16 = lane & 15;
  const int wm   = w >> 1;
  const int wn   = w & 1;
  const int row0 = blockIdx.x * 64;

  const int ar = tid >> 2;
  const int ak = (tid & 3) << 3;
  const int wk = tid >> 3;
  const int wn8 = (tid & 7) << 3;

  f32x4 acc[2][2];
#pragma unroll
  for (int i = 0; i < 2; ++i)
#pragma unroll
    for (int j = 0; j < 2; ++j) acc[i][j] = (f32x4){0.f, 0.f, 0.f, 0.f};

  for (int kt = 0; kt < TD; kt += 32) {
    {
      short8v v = *(const short8v*)(xb + (size_t)(row0 + ar) * TD + kt + ak);
      *(short8v*)&As[ar][ak] = v;
    }
    {
      const float* wp = W + (size_t)(kt + wk) * N + col0 + wn8;
      float4 f0 = *(const float4*)wp;
      float4 f1 = *(const float4*)(wp + 4);
      Bs[wn8 + 0][wk] = (short)f2bf(f0.x);
      Bs[wn8 + 1][wk] = (short)f2bf(f0.y);
      Bs[wn8 + 2][wk] = (short)f2bf(f0.z);
      Bs[wn8 + 3][wk] = (short)f2bf(f0.w);
      Bs[wn8 + 4][wk] = (short)f2bf(f1.x);
      Bs[wn8 + 5][wk] = (short)f2bf(f1.y);
      Bs[wn8 + 6][wk] = (short)f2bf(f1.z);
      Bs[wn8 + 7][wk] = (short)f2bf(f1.w);
    }
    __syncthreads();

    short8v a0 = *(const short8v*)&As[wm * 32 + lc16][g * 8];
    short8v a1 = *(const short8v*)&As[wm * 32 + 16 + lc16][g * 8];
    short8v b0 = *(const short8v*)&Bs[wn * 32 + lc16][g * 8];
    short8v b1 = *(const short8v*)&Bs[wn * 32 + 16 + lc16][g * 8];
    acc[0][0] = __builtin_amdgcn_mfma_f32_16x16x32_bf16(a0, b0, acc[0][0], 0, 0, 0);
    acc[0][1] = __builtin_amdgcn_mfma_f32_16x16x32_bf16(a0, b1, acc[0][1], 0, 0, 0);
    acc[1][0] = __builtin_amdgcn_mfma_f32_16x16x32_bf16(a1, b0, acc[1][0], 0, 0, 0);
    acc[1][1] = __builtin_amdgcn_mfma_f32_16x16x32_bf16(a1, b1, acc[1][1], 0, 0, 0);
    __syncthreads();
  }

  short* Obf = (outsel == 0) ? Qh : Kh;
#pragma unroll
  for (int ni = 0; ni < 2; ++ni) {
    const int ocol = col0 + wn * 32 + ni * 16 + lc16;
    if (ocol >= N) continue;
    const float bb = bias[ocol];
#pragma unroll
    for (int mi = 0; mi < 2; ++mi)
#pragma unroll
      for (int r = 0; r < 4; ++r) {
        const int orow = row0 + wm * 32 + mi * 16 + g * 4 + r;
        const float val = acc[mi][ni][r] + bb;
        if (outsel == 2) {
          Vb[(size_t)orow * TDH + ocol] = val;
        } else {
          const int bI = orow >> 11, s = orow & 2047;
          const int hI = ocol >> 6, dh = ocol & 63;
          Obf[(((size_t)(bI * TH + hI) * TS + s) * TDH) + dh] = (short)f2bf(val);
        }
      }
  }
}

// ---------------------------------------------------------------------------
// Output projection GEMM (proven): x_out = Hd(bf16) @ Wout + bout.
// ---------------------------------------------------------------------------
__global__ __launch_bounds__(256) void gemm_out(
    const short* __restrict__ A, const float* __restrict__ W,
    const float* __restrict__ bias, float* __restrict__ Cf, int N, int Kd)
{
  __shared__ short As[64][40];
  __shared__ short Bs[64][40];

  const int tid  = threadIdx.x;
  const int w    = tid >> 6;
  const int lane = tid & 63;
  const int g    = lane >> 4;
  const int lc16 = lane & 15;
  const int wm   = w >> 1;
  const int wn   = w & 1;
  const int row0 = blockIdx.x * 64;
  const int col0 = blockIdx.y * 64;

  const int ar = tid >> 2;
  const int ak = (tid & 3) << 3;
  const int wk = tid >> 3;
  const int wn8 = (tid & 7) << 3;

  f32x4 acc[2][2];
#pragma unroll
  for (int i = 0; i < 2; ++i)
#pragma unroll
    for (int j = 0; j < 2; ++j) acc[i][j] = (f32x4){0.f, 0.f, 0.f, 0.f};

  for (int kt = 0; kt < Kd; kt += 32) {
    {
      short8v v = *(const short8v*)(A + (size_t)(row0 + ar) * Kd + kt + ak);
      *(short8v*)&As[ar][ak] = v;
    }
    {
      const float* wp = W + (size_t)(kt + wk) * N + col0 + wn8;
      float4 f0 = *(const float4*)wp;
      float4 f1 = *(const float4*)(wp + 4);
      Bs[wn8 + 0][wk] = (short)f2bf(f0.x);
      Bs[wn8 + 1][wk] = (short)f2bf(f0.y);
      Bs[wn8 + 2][wk] = (short)f2bf(f0.z);
      Bs[wn8 + 3][wk] = (short)f2bf(f0.w);
      Bs[wn8 + 4][wk] = (short)f2bf(f1.x);
      Bs[wn8 + 5][wk] = (short)f2bf(f1.y);
      Bs[wn8 + 6][wk] = (short)f2bf(f1.z);
      Bs[wn8 + 7][wk] = (short)f2bf(f1.w);
    }
    __syncthreads();

    short8v a0 = *(const short8v*)&As[wm * 32 + lc16][g * 8];
    short8v a1 = *(const short8v*)&As[wm * 32 + 16 + lc16][g * 8];
    short8v b0 = *(const short8v*)&Bs[wn * 32 + lc16][g * 8];
    short8v b1 = *(const short8v*)&Bs[wn * 32 + 16 + lc16][g * 8];
    acc[0][0] = __builtin_amdgcn_mfma_f32_16x16x32_bf16(a0, b0, acc[0][0], 0, 0, 0);
    acc[0][1] = __builtin_amdgcn_mfma_f32_16x16x32_bf16(a0, b1, acc[0][1], 0, 0, 0);
    acc[1][0] = __builtin_amdgcn_mfma_f32_16x16x32_bf16(a1, b0, acc[1][0], 0, 0, 0);
    acc[1][1] = __builtin_amdgcn_mfma_f32_16x16x32_bf16(a1, b1, acc[1][1], 0, 0, 0);
    __syncthreads();
  }

#pragma unroll
  for (int ni = 0; ni < 2; ++ni) {
    const int ocol = col0 + wn * 32 + ni * 16 + lc16;
    const float bb = bias[ocol];
#pragma unroll
    for (int mi = 0; mi < 2; ++mi)
#pragma unroll
      for (int r = 0; r < 4; ++r) {
        const int orow = row0 + wm * 32 + mi * 16 + g * 4 + r;
        Cf[(size_t)orow * N + ocol] = acc[mi][ni][r] + bb;
      }
  }
}

// ---------------------------------------------------------------------------
// zgemm v2: register NT-GEMM (R8 structure) + LDS transpose for COALESCED
// fp16 Z writes. Block = 64q x 256j, one (pair). After MFMA, the 64x256 fp16
// tile is staged in LDS ([64][264] pad), then written as 512B-contiguous
// runs per half-wave (16B/lane). One barrier, ~33 KB LDS.
// mfma(K,Q): D col = q (lane&15), row = j ((lane>>4)*4+reg).
// ---------------------------------------------------------------------------
__global__ __launch_bounds__(256) void zgemm(
    const short* __restrict__ Qh, const short* __restrict__ Kh,
    _Float16* __restrict__ Zh, int q0s, int qc)
{
  __shared__ _Float16 Zt[64][264];   // pad 8 halfs: read-back row rotate

  const int tid  = threadIdx.x;
  const int w    = tid >> 6;
  const int lane = tid & 63;
  const int g    = lane >> 4;
  const int lc16 = lane & 15;
  const int pair = blockIdx.z;
  const int jb0  = blockIdx.x * 256;
  const int qlb  = blockIdx.y * 64;
  const int qb   = q0s + qlb;

  const short* Qp = Qh + (size_t)pair * TS * TDH;
  const short* Kp = Kh + (size_t)pair * TS * TDH;

  short8v bq[4][2];
#pragma unroll
  for (int ct = 0; ct < 4; ++ct) {
    const short* qp = Qp + (size_t)(qb + ct * 16 + lc16) * TDH + g * 8;
    bq[ct][0] = *(const short8v*)qp;
    bq[ct][1] = *(const short8v*)(qp + 32);
  }

  f32x4 acc[4][4];
#pragma unroll
  for (int rt = 0; rt < 4; ++rt)
#pragma unroll
    for (int ct = 0; ct < 4; ++ct) acc[rt][ct] = (f32x4){0.f, 0.f, 0.f, 0.f};

#pragma unroll
  for (int rt = 0; rt < 4; ++rt) {
    const short* kp = Kp + (size_t)(jb0 + w * 64 + rt * 16 + lc16) * TDH + g * 8;
    short8v ak0 = *(const short8v*)kp;
    short8v ak1 = *(const short8v*)(kp + 32);
#pragma unroll
    for (int ct = 0; ct < 4; ++ct) {
      acc[rt][ct] = __builtin_amdgcn_mfma_f32_16x16x32_bf16(ak0, bq[ct][0], acc[rt][ct], 0, 0, 0);
      acc[rt][ct] = __builtin_amdgcn_mfma_f32_16x16x32_bf16(ak1, bq[ct][1], acc[rt][ct], 0, 0, 0);
    }
  }

  // stage to LDS: row = local q, col = local j
#pragma unroll
  for (int rt = 0; rt < 4; ++rt)
#pragma unroll
    for (int ct = 0; ct < 4; ++ct) {
      half4v o = {(_Float16)acc[rt][ct][0], (_Float16)acc[rt][ct][1],
                  (_Float16)acc[rt][ct][2], (_Float16)acc[rt][ct][3]};
      *(half4v*)&Zt[ct * 16 + lc16][w * 64 + rt * 16 + g * 4] = o;
    }
  __syncthreads();

  // coalesced writeback: iteration i, thread t -> row i*8 + t/32, 16B at (t%32)*8
  const int rseg = tid >> 5;          // 0..7
  const int jseg = (tid & 31) << 3;   // 0..248 step 8
#pragma unroll
  for (int i = 0; i < 8; ++i) {
    const int r = (i << 3) + rseg;
    half8v v = *(const half8v*)&Zt[r][jseg];
    *(half8v*)&Zh[((size_t)pair * qc + qlb + r) * TS + jb0 + jseg] = v;
  }
}

// ---------------------------------------------------------------------------
// spv (R11/R13 structure): one block per (b,q), 512 thr = 8 waves, wave =
// head. Row = 4 x half8 per lane -> f32 regs. Max -> tau0 = zmax-1 -> <=4
// candidates/lane in NAMED regs -> 4-reg Michelot (dense fallback on lane
// overflow) -> support scatter to LDS avg row + PV list -> batched sparse PV
// -> heads; one dense avg write.
// ---------------------------------------------------------------------------
__global__ __launch_bounds__(512) void spv(
    const _Float16* __restrict__ Zh, const float* __restrict__ V,
    short* __restrict__ heads, float* __restrict__ avg,
    int q0s, int qc)
{
  __shared__ float avgS[TS];                 // 8 KB
  __shared__ unsigned short idxW[TH][CAP];   // 4 KB
  __shared__ float pW[TH][CAP];              // 8 KB
  __shared__ int cntW[TH];

  const int tid  = threadIdx.x;
  const int h    = tid >> 6;                 // wave = head
  const int lane = tid & 63;
  const int ql   = blockIdx.x;
  const int bsel = blockIdx.y;
  const int q    = q0s + ql;
  const int row  = bsel * TS + q;
  const float* Vb = V + (size_t)bsel * TS * TDH;

  *(f32x4*)&avgS[tid << 2] = (f32x4){0.f, 0.f, 0.f, 0.f};
  if (lane == 0) cntW[h] = 0;
  __syncthreads();

  // ---- load row (fp16) and convert to f32 regs ----
  float za[4][8];
  const _Float16* zp = Zh + ((size_t)(bsel * TH + h) * qc + ql) * TS;
#pragma unroll
  for (int k = 0; k < 4; ++k) {
    half8v v = *(const half8v*)(zp + (k << 9) + (lane << 3));
#pragma unroll
    for (int c = 0; c < 8; ++c) za[k][c] = (float)v[c];
  }

  // ---- wave row max ----
  float m = za[0][0];
#pragma unroll
  for (int k = 0; k < 4; ++k)
#pragma unroll
    for (int c = 0; c < 8; ++c) m = fmaxf(m, za[k][c]);
#pragma unroll
  for (int s = 1; s < 64; s <<= 1) m = fmaxf(m, __shfl_xor(m, s));
  const float tau0 = m - 1.0f;

  // ---- extract <=4 candidates per lane (named regs, static indexing) ----
  float c0 = -1e30f, c1 = -1e30f, c2 = -1e30f, c3 = -1e30f;
  int j0 = 0, j1 = 0, j2 = 0, j3 = 0, nc = 0;
#pragma unroll
  for (int k = 0; k < 4; ++k)
#pragma unroll
    for (int c = 0; c < 8; ++c) {
      const float v = za[k][c];
      if (v > tau0) {
        c3 = c2; j3 = j2; c2 = c1; j2 = j1; c1 = c0; j1 = j0;
        c0 = v; j0 = (k << 9) + (lane << 3) + c; ++nc;
      }
    }
  const bool over = (__ballot(nc > 4) != 0ull);

  // ---- Michelot fixpoint (exact tau) ----
  float tau = tau0;
  int prevc = -1;
  if (!over) {
    for (int it = 0; it < 64; ++it) {
      float s = 0.f, c = 0.f;
      if (c0 > tau) { s += c0; c += 1.f; }
      if (c1 > tau) { s += c1; c += 1.f; }
      if (c2 > tau) { s += c2; c += 1.f; }
      if (c3 > tau) { s += c3; c += 1.f; }
#pragma unroll
      for (int sh = 1; sh < 64; sh <<= 1) {
        s += __shfl_xor(s, sh);
        c += __shfl_xor(c, sh);
      }
      tau = (s - 1.f) / c;
      const int ci = (int)c;
      if (ci == prevc) break;
      prevc = ci;
    }
  } else {
    for (int it = 0; it < 64; ++it) {
      float s = 0.f, c = 0.f;
#pragma unroll
      for (int k = 0; k < 4; ++k)
#pragma unroll
        for (int cc = 0; cc < 8; ++cc) {
          const float v = za[k][cc];
          if (v > tau) { s += v; c += 1.f; }
        }
#pragma unroll
      for (int sh = 1; sh < 64; sh <<= 1) {
        s += __shfl_xor(s, sh);
        c += __shfl_xor(c, sh);
      }
      tau = (s - 1.f) / c;
      const int ci = (int)c;
      if (ci == prevc) break;
      prevc = ci;
    }
  }

  // ---- emit support: avg scatter + PV list ----
  if (!over) {
    {
      const float p = c0 - tau;
      if (p > 0.f) {
        atomicAdd(&avgS[j0], p);
        const int pos = atomicAdd(&cntW[h], 1);
        if (pos < CAP) { idxW[h][pos] = (unsigned short)j0; pW[h][pos] = p; }
      }
    }
    {
      const float p = c1 - tau;
      if (p > 0.f) {
        atomicAdd(&avgS[j1], p);
        const int pos = atomicAdd(&cntW[h], 1);
        if (pos < CAP) { idxW[h][pos] = (unsigned short)j1; pW[h][pos] = p; }
      }
    }
    {
      const float p = c2 - tau;
      if (p > 0.f) {
        atomicAdd(&avgS[j2], p);
        const int pos = atomicAdd(&cntW[h], 1);
        if (pos < CAP) { idxW[h][pos] = (unsigned short)j2; pW[h][pos] = p; }
      }
    }
    {
      const float p = c3 - tau;
      if (p > 0.f) {
        atomicAdd(&avgS[j3], p);
        const int pos = atomicAdd(&cntW[h], 1);
        if (pos < CAP) { idxW[h][pos] = (unsigned short)j3; pW[h][pos] = p; }
      }
    }
  } else {
#pragma unroll
    for (int k = 0; k < 4; ++k)
#pragma unroll
      for (int cc = 0; cc < 8; ++cc) {
        const float p = za[k][cc] - tau;
        if (p > 0.f) {
          const int j = (k << 9) + (lane << 3) + cc;
          atomicAdd(&avgS[j], p);
          const int pos = atomicAdd(&cntW[h], 1);
          if (pos < CAP) { idxW[h][pos] = (unsigned short)j; pW[h][pos] = p; }
        }
      }
  }

  // ---- PV (wave-local list; cnt visible in program order) ----
  const int cnt = cntW[h];
  float a = 0.f;
  if (cnt <= CAP) {
    for (int e0 = 0; e0 < cnt; e0 += 8) {
      float pb[8], vb8[8];
#pragma unroll
      for (int u = 0; u < 8; ++u) {
        const int e = e0 + u;
        const int ec = (e < cnt) ? e : 0;
        pb[u] = (e < cnt) ? pW[h][ec] : 0.f;
        vb8[u] = Vb[(size_t)idxW[h][ec] * TDH + lane];
      }
#pragma unroll
      for (int u = 0; u < 8; ++u) a += pb[u] * vb8[u];
    }
  } else {
    // ballot-serial dense fallback (support > CAP; essentially never)
#pragma unroll
    for (int k = 0; k < 4; ++k)
#pragma unroll
      for (int cc = 0; cc < 8; ++cc) {
        const float p = za[k][cc] - tau;
        unsigned long long mask = __ballot(p > 0.f);
        while (mask) {
          const int src = __ffsll((long long)mask) - 1;
          mask &= mask - 1;
          const float pj = __shfl(p, src);
          const int j = (k << 9) + (src << 3) + cc;
          a += pj * Vb[(size_t)j * TDH + lane];
        }
      }
  }
  heads[(size_t)row * TD + h * TDH + lane] = (short)f2bf(a);

  // ---- dense avg write ----
  __syncthreads();
  {
    f32x4 t = *(const f32x4*)&avgS[tid << 2];
    float4 o = {t[0] * 0.125f, t[1] * 0.125f, t[2] * 0.125f, t[3] * 0.125f};
    *(float4*)(avg + (size_t)row * TS + (tid << 2)) = o;
  }
}

// ---------------------------------------------------------------------------
extern "C" void kernel_launch(void* const* d_in, const int* in_sizes, int n_in,
                              void* d_out, int out_size, void* d_ws, size_t ws_size,
                              hipStream_t stream) {
  (void)in_sizes; (void)n_in; (void)out_size;

  const float* x    = (const float*)d_in[0];
  const float* Wq   = (const float*)d_in[1];
  const float* bq   = (const float*)d_in[2];
  const float* Wk   = (const float*)d_in[3];
  const float* bk   = (const float*)d_in[4];
  const float* Wv   = (const float*)d_in[5];
  const float* bv   = (const float*)d_in[6];
  const float* Wout = (const float*)d_in[7];
  const float* bout = (const float*)d_in[8];

  float* out   = (float*)d_out;
  float* x_out = out;                       // [2,2048,512]
  float* avg   = out + 2097152;             // [2,2048,2048]

  float* ws = (float*)d_ws;
  float* Vb = ws;                           // f32 [2][2048][64]   (262144 fl)
  short* Hd = (short*)(ws + 262144);        // bf16 [4096][512]    (1048576 fl)
  short* Qh = (short*)(ws + 1310720);       // bf16 [16][2048][64] (1048576 fl)
  short* Kh = (short*)(ws + 2359296);       // bf16 [16][2048][64] (1048576 fl)
  _Float16* Zh = (_Float16*)(ws + 3407872); // fp16 slab [16][qc][2048]
  // xb ALIASES the head of the Zh slab: consumed by proj_gemm BEFORE any
  // zgemm writes Z (stream-ordered), re-written by cvt_bf16 every replay.
  short* xbuf = (short*)(ws + 3407872);     // bf16 [4096][512] (1048576 fl)

  // largest q-chunk (both batches resident: 16 pairs) fitting the workspace
  const size_t wsFloats = ws_size / 4;
  const size_t base = 3407872;
  int qc = 64;
  for (int cand = 2048; cand >= 64; cand >>= 1) {
    if (base + (size_t)16 * cand * 1024 <= wsFloats) { qc = cand; break; }
  }

  const dim3 blk(256);
  const int BS = 2 * TS;                    // 4096 rows

  // x -> bf16 once, then fused QKV projections reading bf16
  cvt_bf16<<<dim3(BS * TD / (256 * 8)), blk, 0, stream>>>(x, xbuf);
  proj_gemm<<<dim3(BS / 64, 17), blk, 0, stream>>>(xbuf, Wq, bq, Wk, bk, Wv, bv, Qh, Kh, Vb);

  // attention: both batches per launch, slabbed over q-chunks
  for (int q0s = 0; q0s < TS; q0s += qc) {
    zgemm<<<dim3(TS / 256, qc / 64, 16), blk, 0, stream>>>(Qh, Kh, Zh, q0s, qc);
    spv<<<dim3(qc, 2), dim3(512), 0, stream>>>(Zh, Vb, Hd, avg, q0s, qc);
  }

  // output projection
  gemm_out<<<dim3(BS / 64, TD / 64), blk, 0, stream>>>(Hd, Wout, bout, x_out, TD, TD);
}